// Round 1
// baseline (1694.711 us; speedup 1.0000x reference)
//
#include <hip/hip_runtime.h>

#define NEG 0.01f

__device__ __forceinline__ float lrelu(float v) { return v >= 0.f ? v : NEG * v; }

__global__ __launch_bounds__(256, 2) void braggnn_fused(
    const float* __restrict__ x,
    const float* __restrict__ w1, const float* __restrict__ b1,
    const float* __restrict__ wt, const float* __restrict__ bt,
    const float* __restrict__ wp, const float* __restrict__ bp,
    const float* __restrict__ wg, const float* __restrict__ bg,
    const float* __restrict__ wo, const float* __restrict__ bo,
    const float* __restrict__ w2, const float* __restrict__ b2,
    const float* __restrict__ w3, const float* __restrict__ b3,
    const float* __restrict__ dw1, const float* __restrict__ db1,
    const float* __restrict__ dw2, const float* __restrict__ db2,
    const float* __restrict__ dw3, const float* __restrict__ db3,
    const float* __restrict__ dw4, const float* __restrict__ db4,
    const float* __restrict__ dw5, const float* __restrict__ db5,
    float* __restrict__ out)
{
  const int b = blockIdx.x;
  const int t = threadIdx.x;

  // h stored [64][9 rows][stride 12] so conv2 can do aligned float4 row reads
  __shared__ __align__(16) float xs[128];
  __shared__ __align__(16) float h[64 * 108];
  __shared__ __align__(16) float sb[32 * 81];   // theta*phi scores
  __shared__ __align__(16) float gb[32 * 81];   // g, then attn*g in place
  __shared__ __align__(16) float c2s[32 * 56];  // conv2 out [32][7][stride 8]
  __shared__ __align__(16) float c3s[200];      // conv3 out, flatten order [8][5][5]
  __shared__ float d1p[256];
  __shared__ float d1[64];
  __shared__ float d2[32];
  __shared__ float d3[16];
  __shared__ float d4[8];

  // ---- stage 0: load input patch (11x11) ----
  if (t < 121) xs[t] = x[(size_t)b * 121 + t];
  __syncthreads();

  // ---- stage 1: conv1 1->64, 3x3 valid -> h [64][9][9] (NO activation) ----
  for (int i = t; i < 64 * 81; i += 256) {
    int oc = i / 81, px = i % 81;
    int y = px / 9, xx = px % 9;
    float acc = b1[oc];
    const float* wr = &w1[oc * 9];
#pragma unroll
    for (int ky = 0; ky < 3; ky++)
#pragma unroll
      for (int kx = 0; kx < 3; kx++)
        acc = fmaf(xs[(y + ky) * 11 + xx + kx], wr[ky * 3 + kx], acc);
    h[oc * 108 + y * 12 + xx] = acc;
  }
  __syncthreads();

  // ---- stage 2: theta/phi/g 1x1 convs (64->32), fused; sb = theta*phi ----
  // 3 pixels per item so one weight fetch feeds 3 FMAs per tensor.
  for (int j = t; j < 32 * 27; j += 256) {
    int oc = j / 27, p = j % 27;
    int px0 = p, px1 = p + 27, px2 = p + 54;
    int o0 = (px0 / 9) * 12 + px0 % 9;
    int o1 = (px1 / 9) * 12 + px1 % 9;
    int o2 = (px2 / 9) * 12 + px2 % 9;
    float tb = bt[oc], pbv = bp[oc], gbv = bg[oc];
    float t0 = tb, t1 = tb, t2 = tb;
    float p0 = pbv, p1 = pbv, p2 = pbv;
    float g0 = gbv, g1 = gbv, g2 = gbv;
    const float* wtr = &wt[oc * 64];
    const float* wpr = &wp[oc * 64];
    const float* wgr = &wg[oc * 64];
#pragma unroll 8
    for (int k = 0; k < 64; k++) {
      float h0 = h[k * 108 + o0], h1v = h[k * 108 + o1], h2v = h[k * 108 + o2];
      float wtv = wtr[k], wpv = wpr[k], wgv = wgr[k];
      t0 = fmaf(wtv, h0, t0); t1 = fmaf(wtv, h1v, t1); t2 = fmaf(wtv, h2v, t2);
      p0 = fmaf(wpv, h0, p0); p1 = fmaf(wpv, h1v, p1); p2 = fmaf(wpv, h2v, p2);
      g0 = fmaf(wgv, h0, g0); g1 = fmaf(wgv, h1v, g1); g2 = fmaf(wgv, h2v, g2);
    }
    sb[oc * 81 + px0] = t0 * p0; sb[oc * 81 + px1] = t1 * p1; sb[oc * 81 + px2] = t2 * p2;
    gb[oc * 81 + px0] = g0;      gb[oc * 81 + px1] = g1;      gb[oc * 81 + px2] = g2;
  }
  __syncthreads();

  // ---- stage 3: softmax over W (rows of 9), then gb = attn * g in place ----
  for (int r = t; r < 32 * 9; r += 256) {
    int base = (r / 9) * 81 + (r % 9) * 9;
    float v[9];
    float m = -1e30f;
#pragma unroll
    for (int k = 0; k < 9; k++) { v[k] = sb[base + k]; m = fmaxf(m, v[k]); }
    float s = 0.f;
#pragma unroll
    for (int k = 0; k < 9; k++) { v[k] = __expf(v[k] - m); s += v[k]; }
    float inv = 1.f / s;
#pragma unroll
    for (int k = 0; k < 9; k++) gb[base + k] *= v[k] * inv;
  }
  __syncthreads();

  // ---- stage 4: h = lrelu(conv1x1(attn*g, wo) + h) in place ----
  for (int j = t; j < 64 * 27; j += 256) {
    int oc = j / 27, p = j % 27;
    int px0 = p, px1 = p + 27, px2 = p + 54;
    int o0 = (px0 / 9) * 12 + px0 % 9;
    int o1 = (px1 / 9) * 12 + px1 % 9;
    int o2 = (px2 / 9) * 12 + px2 % 9;
    float bv = bo[oc];
    float a0 = bv, a1 = bv, a2 = bv;
    const float* wor = &wo[oc * 32];
#pragma unroll 8
    for (int k = 0; k < 32; k++) {
      float wv = wor[k];
      a0 = fmaf(wv, gb[k * 81 + px0], a0);
      a1 = fmaf(wv, gb[k * 81 + px1], a1);
      a2 = fmaf(wv, gb[k * 81 + px2], a2);
    }
    int i0 = oc * 108 + o0, i1 = oc * 108 + o1, i2 = oc * 108 + o2;
    h[i0] = lrelu(h[i0] + a0);
    h[i1] = lrelu(h[i1] + a1);
    h[i2] = lrelu(h[i2] + a2);
  }
  __syncthreads();

  // ---- stage 5: conv2 64->32, 3x3 on h -> c2s [32][7][7], lrelu ----
  if (t < 224) {
    int oc = t / 7, y = t % 7;
    float acc[7];
    float bv = b2[oc];
#pragma unroll
    for (int xx = 0; xx < 7; xx++) acc[xx] = bv;
    for (int ic = 0; ic < 64; ic++) {
#pragma unroll
      for (int ky = 0; ky < 3; ky++) {
        const float4* rp = reinterpret_cast<const float4*>(&h[ic * 108 + (y + ky) * 12]);
        float4 ra = rp[0], rb = rp[1], rc = rp[2];
        float row[12] = {ra.x, ra.y, ra.z, ra.w, rb.x, rb.y, rb.z, rb.w,
                         rc.x, rc.y, rc.z, rc.w};
        const float* wr = &w2[((oc * 64 + ic) * 3 + ky) * 3];
        float w0 = wr[0], w1v = wr[1], w2v = wr[2];
#pragma unroll
        for (int xx = 0; xx < 7; xx++)
          acc[xx] = fmaf(row[xx], w0,
                    fmaf(row[xx + 1], w1v,
                    fmaf(row[xx + 2], w2v, acc[xx])));
      }
    }
#pragma unroll
    for (int xx = 0; xx < 7; xx++) c2s[oc * 56 + y * 8 + xx] = lrelu(acc[xx]);
  }
  __syncthreads();

  // ---- stage 6: conv3 32->8, 3x3 on c2s -> c3s [8][5][5], lrelu ----
  if (t < 200) {
    int oc = t / 25, px = t % 25;
    int y = px / 5, xx = px % 5;
    float acc = b3[oc];
    for (int ic = 0; ic < 32; ic++) {
#pragma unroll
      for (int ky = 0; ky < 3; ky++) {
        const float* rp = &c2s[ic * 56 + (y + ky) * 8 + xx];
        const float* wr = &w3[((oc * 32 + ic) * 3 + ky) * 3];
        acc = fmaf(rp[0], wr[0], acc);
        acc = fmaf(rp[1], wr[1], acc);
        acc = fmaf(rp[2], wr[2], acc);
      }
    }
    c3s[oc * 25 + px] = lrelu(acc);
  }
  __syncthreads();

  // ---- stage 7: dense 200->64 (chunked partial sums) ----
  {
    int o = t & 63, chunk = t >> 6;  // 4 chunks of 50
    float acc = 0.f;
    const float* wr = &dw1[o * 200 + chunk * 50];
    const float* cr = &c3s[chunk * 50];
#pragma unroll 10
    for (int k = 0; k < 50; k++) acc = fmaf(wr[k], cr[k], acc);
    d1p[chunk * 64 + o] = acc;
  }
  __syncthreads();
  if (t < 64) {
    float v = d1p[t] + d1p[64 + t] + d1p[128 + t] + d1p[192 + t] + db1[t];
    d1[t] = lrelu(v);
  }
  __syncthreads();

  // ---- stage 8: dense 64->32 ----
  if (t < 32) {
    float acc = db2[t];
    const float* wr = &dw2[t * 64];
#pragma unroll 8
    for (int k = 0; k < 64; k++) acc = fmaf(wr[k], d1[k], acc);
    d2[t] = lrelu(acc);
  }
  __syncthreads();

  // ---- stage 9: dense 32->16 ----
  if (t < 16) {
    float acc = db3[t];
    const float* wr = &dw3[t * 32];
#pragma unroll 8
    for (int k = 0; k < 32; k++) acc = fmaf(wr[k], d2[k], acc);
    d3[t] = lrelu(acc);
  }
  __syncthreads();

  // ---- stage 10: dense 16->8 ----
  if (t < 8) {
    float acc = db4[t];
    const float* wr = &dw4[t * 16];
#pragma unroll
    for (int k = 0; k < 16; k++) acc = fmaf(wr[k], d3[k], acc);
    d4[t] = lrelu(acc);
  }
  __syncthreads();

  // ---- stage 11: dense 8->2, write out ----
  if (t < 2) {
    float acc = db5[t];
    const float* wr = &dw5[t * 8];
#pragma unroll
    for (int k = 0; k < 8; k++) acc = fmaf(wr[k], d4[k], acc);
    out[(size_t)b * 2 + t] = acc;
  }
}

extern "C" void kernel_launch(void* const* d_in, const int* in_sizes, int n_in,
                              void* d_out, int out_size, void* d_ws, size_t ws_size,
                              hipStream_t stream) {
  const float* x   = (const float*)d_in[0];
  const float* w1  = (const float*)d_in[1];
  const float* b1  = (const float*)d_in[2];
  const float* wt  = (const float*)d_in[3];
  const float* bt  = (const float*)d_in[4];
  const float* wp  = (const float*)d_in[5];
  const float* bp  = (const float*)d_in[6];
  const float* wg  = (const float*)d_in[7];
  const float* bg  = (const float*)d_in[8];
  const float* wo  = (const float*)d_in[9];
  const float* bo  = (const float*)d_in[10];
  const float* w2  = (const float*)d_in[11];
  const float* b2  = (const float*)d_in[12];
  const float* w3  = (const float*)d_in[13];
  const float* b3  = (const float*)d_in[14];
  const float* dw1 = (const float*)d_in[15];
  const float* db1 = (const float*)d_in[16];
  const float* dw2 = (const float*)d_in[17];
  const float* db2 = (const float*)d_in[18];
  const float* dw3 = (const float*)d_in[19];
  const float* db3 = (const float*)d_in[20];
  const float* dw4 = (const float*)d_in[21];
  const float* db4 = (const float*)d_in[22];
  const float* dw5 = (const float*)d_in[23];
  const float* db5 = (const float*)d_in[24];

  int B = in_sizes[0] / 121;
  braggnn_fused<<<B, 256, 0, stream>>>(
      x, w1, b1, wt, bt, wp, bp, wg, bg, wo, bo, w2, b2, w3, b3,
      dw1, db1, dw2, db2, dw3, db3, dw4, db4, dw5, db5,
      (float*)d_out);
}